// Round 7
// baseline (289.068 us; speedup 1.0000x reference)
//
#include <hip/hip_runtime.h>
#include <hip/hip_bf16.h>
#include <math.h>

#define NNODES 100000
#define NEDGES 1600000
#define NB 782           // ceil(NNODES/128) buckets of 128 nodes
#define PB 256           // partition blocks
#define EPB 6250         // NEDGES / PB exactly
#define SCAN_N (NB * PB) // 200192
#define CAP 4608         // LDS stage capacity per bucket (avg 2048, max ~2300)

typedef __bf16 bf16x8 __attribute__((ext_vector_type(8)));
typedef float f32x4 __attribute__((ext_vector_type(4)));
typedef float f32x8 __attribute__((ext_vector_type(8)));

static __device__ inline unsigned short f2bf(float f) {
    __hip_bfloat16 h = __float2bfloat16(f);
    return *reinterpret_cast<unsigned short*>(&h);
}

// ---------------- pass A: per-block LDS histogram of dst>>7 ----------------

__global__ __launch_bounds__(256) void hist_kernel(const int* __restrict__ dst,
                                                   int* __restrict__ histg) {
    __shared__ int h[NB];
    int tid = threadIdx.x, blk = blockIdx.x;
    for (int b = tid; b < NB; b += 256) h[b] = 0;
    __syncthreads();
    int base = blk * EPB;
    for (int i = base + tid; i < base + EPB; i += 256)
        atomicAdd(&h[dst[i] >> 7], 1);
    __syncthreads();
    for (int b = tid; b < NB; b += 256) histg[b * PB + blk] = h[b];
}

// ---------------- scan chain over SCAN_N elements ----------------

__global__ __launch_bounds__(256) void scan1_kernel(const int* __restrict__ cnt,
                                                    int* __restrict__ off,
                                                    int* __restrict__ bsum, int n) {
    __shared__ int tmp[256];
    int tid = threadIdx.x;
    int t4 = blockIdx.x * 1024 + tid * 4;
    int v0 = (t4 + 0 < n) ? cnt[t4 + 0] : 0;
    int v1 = (t4 + 1 < n) ? cnt[t4 + 1] : 0;
    int v2 = (t4 + 2 < n) ? cnt[t4 + 2] : 0;
    int v3 = (t4 + 3 < n) ? cnt[t4 + 3] : 0;
    int ssum = v0 + v1 + v2 + v3;
    tmp[tid] = ssum;
    __syncthreads();
    for (int d = 1; d < 256; d <<= 1) {
        int x = (tid >= d) ? tmp[tid - d] : 0;
        __syncthreads();
        tmp[tid] += x;
        __syncthreads();
    }
    int run = tmp[tid] - ssum;
    if (t4 + 0 < n) off[t4 + 0] = run; run += v0;
    if (t4 + 1 < n) off[t4 + 1] = run; run += v1;
    if (t4 + 2 < n) off[t4 + 2] = run; run += v2;
    if (t4 + 3 < n) off[t4 + 3] = run;
    if (tid == 255) bsum[blockIdx.x] = tmp[255];
}

__global__ __launch_bounds__(256) void scan2_kernel(const int* __restrict__ bsum,
                                                    int* __restrict__ bsum_ex, int nb) {
    __shared__ int tmp[256];
    int tid = threadIdx.x;
    int v = (tid < nb) ? bsum[tid] : 0;
    tmp[tid] = v;
    __syncthreads();
    for (int d = 1; d < 256; d <<= 1) {
        int x = (tid >= d) ? tmp[tid - d] : 0;
        __syncthreads();
        tmp[tid] += x;
        __syncthreads();
    }
    bsum_ex[tid] = tmp[tid] - v;
}

__global__ __launch_bounds__(256) void scan3t_kernel(const int* __restrict__ part_scan,
                                                     const int* __restrict__ bsum_ex,
                                                     int* __restrict__ gbaseT, int n) {
    int i = blockIdx.x * 256 + threadIdx.x;
    if (i < n) {
        int v = part_scan[i] + bsum_ex[i >> 10];
        int b = i >> 8, blk = i & 255;
        gbaseT[blk * NB + b] = v;
    }
}

// ---------------- pass B: partition edges into bucket-ordered array ----------------

__global__ __launch_bounds__(256) void part_kernel(const int* __restrict__ src,
                                                   const int* __restrict__ dst,
                                                   const int* __restrict__ gbaseT,
                                                   unsigned int* __restrict__ part) {
    __shared__ int gcol[NB];
    __shared__ int cur[NB];
    int tid = threadIdx.x, blk = blockIdx.x;
    for (int b = tid; b < NB; b += 256) {
        gcol[b] = gbaseT[blk * NB + b];
        cur[b] = 0;
    }
    __syncthreads();
    int base = blk * EPB;
    for (int i = base + tid; i < base + EPB; i += 256) {
        int s = src[i], d = dst[i];
        int bkt = d >> 7;
        int r = atomicAdd(&cur[bkt], 1);
        part[gcol[bkt] + r] = ((unsigned int)(d & 127) << 17) | (unsigned int)s;
    }
}

// ---------------- pass C: per-bucket CSR build + cnt/off/dinv ----------------

__global__ __launch_bounds__(256) void csr_kernel(const unsigned int* __restrict__ part,
                                                  const int* __restrict__ gbaseT,
                                                  int* __restrict__ csr,
                                                  int* __restrict__ cnt_g,
                                                  int* __restrict__ off_g,
                                                  float* __restrict__ dinv_g, int n) {
    __shared__ unsigned int stage[CAP];
    __shared__ int hist2[128];
    __shared__ int sc[128];
    __shared__ int excl[128];
    __shared__ int cur2[128];
    int tid = threadIdx.x, b = blockIdx.x;
    int S = gbaseT[b];
    int T = (b == NB - 1) ? NEDGES : gbaseT[b + 1];
    int len = T - S;
    bool fit = (len <= CAP);
    if (tid < 128) { hist2[tid] = 0; cur2[tid] = 0; }
    __syncthreads();
    for (int i = tid; i < len; i += 256) {
        unsigned int p = part[S + i];
        if (fit) stage[i] = p;
        atomicAdd(&hist2[p >> 17], 1);
    }
    __syncthreads();
    if (tid < 128) sc[tid] = hist2[tid];
    __syncthreads();
    for (int d = 1; d < 128; d <<= 1) {
        int x = 0;
        if (tid < 128 && tid >= d) x = sc[tid - d];
        __syncthreads();
        if (tid < 128) sc[tid] += x;
        __syncthreads();
    }
    if (tid < 128) {
        int c = hist2[tid];
        int ex = sc[tid] - c;
        excl[tid] = ex;
        int node = b * 128 + tid;
        if (node < n) {
            cnt_g[node] = c;
            off_g[node] = S + ex;
            dinv_g[node] = rsqrtf((float)c + 1.0f);
        }
    }
    __syncthreads();
    for (int i = tid; i < len; i += 256) {
        unsigned int p = fit ? stage[i] : part[S + i];
        int dl = p >> 17;
        int s = (int)(p & 0x1FFFFu);
        int r = atomicAdd(&cur2[dl], 1);
        csr[S + excl[dl] + r] = s;
    }
}

// ---------------- fused prep: packW1, packW2, W34=W3@W4 (packed), b34, pad-row zero ----
// blocks 0-31: packW1 (K=128). 32-47: packW2 (K=64). 48: zero hp pad row.
// 49-64: W34 compute+pack (4 rows each). 65: b34 = b3@W4 + b4.

static __device__ inline int packidx64(int k, int ch) {
    // packed layout for K=64 (S=2): idx = ((t*2+s)*64 + lane)*8 + ii
    int s = k >> 5, r5 = k & 31, q = r5 >> 3, ii = r5 & 7;
    int t = ch >> 4, lo = ch & 15;
    int lane = q * 16 + lo;
    return ((t * 2 + s) * 64 + lane) * 8 + ii;
}

__global__ __launch_bounds__(256) void prep_kernel(const float* __restrict__ W1,
                                                   const float* __restrict__ W2,
                                                   const float* __restrict__ W3,
                                                   const float* __restrict__ W4,
                                                   const float* __restrict__ b3,
                                                   const float* __restrict__ b4,
                                                   unsigned short* __restrict__ Wp1,
                                                   unsigned short* __restrict__ Wp2,
                                                   unsigned short* __restrict__ Wp34,
                                                   float* __restrict__ b34,
                                                   unsigned short* __restrict__ hp) {
    int blk = blockIdx.x, tid = threadIdx.x;
    if (blk < 32) {            // packW1, K=128, S=4
        int idx = blk * 256 + tid;  // < 8192
        int i = idx & 7, rest = idx >> 3;
        int lane = rest & 63; rest >>= 6;
        int s = rest % 4, t = rest / 4;
        int k = s * 32 + (lane >> 4) * 8 + i;
        int ch = t * 16 + (lane & 15);
        Wp1[idx] = f2bf(W1[k * 64 + ch]);
    } else if (blk < 48) {     // packW2, K=64, S=2
        int idx = (blk - 32) * 256 + tid;  // < 4096
        int i = idx & 7, rest = idx >> 3;
        int lane = rest & 63; rest >>= 6;
        int s = rest % 2, t = rest / 2;
        int k = s * 32 + (lane >> 4) * 8 + i;
        int ch = t * 16 + (lane & 15);
        Wp2[idx] = f2bf(W2[k * 64 + ch]);
    } else if (blk == 48) {    // zero pad row
        if (tid < 64) hp[(size_t)NNODES * 64 + tid] = 0;
    } else if (blk < 65) {     // W34 compute + pack
        int i = (blk - 49) * 4 + (tid >> 6);  // k-dim row of W34
        int j = tid & 63;                      // ch
        float a = 0.f;
        for (int k = 0; k < 256; ++k) a = fmaf(W3[i * 256 + k], W4[k * 64 + j], a);
        Wp34[packidx64(i, j)] = f2bf(a);
    } else {                   // b34
        if (tid < 64) {
            int j = tid;
            float a = b4[j];
            for (int k = 0; k < 256; ++k) a = fmaf(b3[k], W4[k * 64 + j], a);
            b34[j] = a;
        }
    }
}

// ---------------- MFMA GEMM: out[N,64] = X[N,K] @ W[K,64] ----------------

template <int K, bool LSM, bool F32IN>
__global__ __launch_bounds__(256) void gemm_mfma_kernel(const unsigned short* __restrict__ Xb,
                                                        const float* __restrict__ Xf,
                                                        const unsigned short* __restrict__ Wp,
                                                        const float* __restrict__ bias,
                                                        const float* __restrict__ dinv,
                                                        unsigned short* __restrict__ outb,
                                                        float* __restrict__ outf, int n) {
    constexpr int S = K / 32;
    int w = threadIdx.x >> 6, lane = threadIdx.x & 63;
    int q = lane >> 4, lo = lane & 15;
    int base = blockIdx.x * 64 + w * 16;
    int nodeA = base + lo;
    int na = nodeA < n ? nodeA : 0;

    f32x4 acc[4] = {};
#pragma unroll
    for (int s = 0; s < S; ++s) {
        bf16x8 a;
        if (F32IN) {
            const float* xr = Xf + (size_t)na * K + q * 8 + s * 32;
            float4 u = *(const float4*)(xr);
            float4 v = *(const float4*)(xr + 4);
            a[0] = (__bf16)u.x; a[1] = (__bf16)u.y; a[2] = (__bf16)u.z; a[3] = (__bf16)u.w;
            a[4] = (__bf16)v.x; a[5] = (__bf16)v.y; a[6] = (__bf16)v.z; a[7] = (__bf16)v.w;
        } else {
            a = *(const bf16x8*)(Xb + (size_t)na * K + q * 8 + s * 32);
        }
#pragma unroll
        for (int t = 0; t < 4; ++t) {
            bf16x8 b = *(const bf16x8*)(Wp + ((size_t)(t * S + s) * 64 + lane) * 8);
            acc[t] = __builtin_amdgcn_mfma_f32_16x16x32_bf16(a, b, acc[t], 0, 0, 0);
        }
    }

    if (!LSM) {
#pragma unroll
        for (int r = 0; r < 4; ++r) {
            int node = base + q * 4 + r;
            if (node < n) {
                float di = dinv[node];
#pragma unroll
                for (int t = 0; t < 4; ++t)
                    outb[(size_t)node * 64 + t * 16 + lo] = f2bf(acc[t][r] * di);
            }
        }
    } else {
#pragma unroll
        for (int r = 0; r < 4; ++r) {
            int node = base + q * 4 + r;
            float v0 = acc[0][r] + bias[0 * 16 + lo];
            float v1 = acc[1][r] + bias[1 * 16 + lo];
            float v2 = acc[2][r] + bias[2 * 16 + lo];
            float v3 = acc[3][r] + bias[3 * 16 + lo];
            float mx = fmaxf(fmaxf(v0, v1), fmaxf(v2, v3));
            for (int d = 1; d < 16; d <<= 1) mx = fmaxf(mx, __shfl_xor(mx, d));
            float sm = __expf(v0 - mx) + __expf(v1 - mx) + __expf(v2 - mx) + __expf(v3 - mx);
            for (int d = 1; d < 16; d <<= 1) sm += __shfl_xor(sm, d);
            float lse = mx + __logf(sm);
            if (node < n) {
                outf[(size_t)node * 64 + 0 * 16 + lo] = v0 - lse;
                outf[(size_t)node * 64 + 1 * 16 + lo] = v1 - lse;
                outf[(size_t)node * 64 + 2 * 16 + lo] = v2 - lse;
                outf[(size_t)node * 64 + 3 * 16 + lo] = v3 - lse;
            }
        }
    }
}

// ---------------- aggregation: one wave per dst node ----------------
// Neighbor BYTE offsets preloaded in one coalesced load (pre-shifted <<7);
// per-iter indices via __shfl; x2 unroll; f32x8 vector accumulate
// (convertvector + packed adds). 8 edges/gather instr, 8 ch/lane.

__global__ __launch_bounds__(256) void aggregate_kernel(const unsigned short* __restrict__ hp,
                                                        const int* __restrict__ csr,
                                                        const int* __restrict__ off,
                                                        const int* __restrict__ cnt,
                                                        const float* __restrict__ dinv,
                                                        const float* __restrict__ bias,
                                                        unsigned short* __restrict__ out, int n) {
    int wid = (blockIdx.x * 256 + threadIdx.x) >> 6;
    int lane = threadIdx.x & 63;
    if (wid >= n) return;
    int g = lane >> 3;         // edge slot 0..7
    int cb = (lane & 7) * 16;  // channel base, BYTES (8 ch x 2B)

    int s = off[wid];
    int c = cnt[wid];

    // preload byte offsets: slots [0,c) = neighbors, slot c = self, rest = pad row
    int ob = n << 7;
    if (lane < c) ob = csr[s + lane] << 7;
    else if (lane == c) ob = wid << 7;   // only reachable when c <= 63

    int m = (c <= 63) ? c + 1 : 64;
    int steps = (m + 7) >> 3;

    const char* hb = (const char*)hp;
    f32x8 acc0 = {}, acc1 = {};
    int it = 0;
    for (; it + 2 <= steps; it += 2) {
        int oa = __shfl(ob, it * 8 + g);
        int oc = __shfl(ob, it * 8 + 8 + g);
        bf16x8 va = *(const bf16x8*)(hb + oa + cb);
        bf16x8 vb = *(const bf16x8*)(hb + oc + cb);
        acc0 += __builtin_convertvector(va, f32x8);
        acc1 += __builtin_convertvector(vb, f32x8);
    }
    if (it < steps) {
        int oa = __shfl(ob, it * 8 + g);
        bf16x8 va = *(const bf16x8*)(hb + oa + cb);
        acc0 += __builtin_convertvector(va, f32x8);
    }

    if (c > 63) {  // rare tail: remaining edges + self-loop
        if (g == 0) {
            bf16x8 v = *(const bf16x8*)(hb + ((size_t)wid << 7) + cb);
            acc1 += __builtin_convertvector(v, f32x8);
        }
        for (int jj = 64 + g; jj < c; jj += 8) {
            int srcn = csr[s + jj];
            bf16x8 v = *(const bf16x8*)(hb + ((size_t)srcn << 7) + cb);
            acc0 += __builtin_convertvector(v, f32x8);
        }
    }

    acc0 += acc1;

    // combine the 8 edge-groups (lanes stride-8 share a channel range)
#pragma unroll
    for (int d = 8; d < 64; d <<= 1) {
        f32x8 t;
#pragma unroll
        for (int j = 0; j < 8; ++j) t[j] = __shfl_xor(acc0[j], d);
        acc0 += t;
    }

    if (lane < 8) {
        int c8 = lane * 8;
        float di = dinv[wid];
        float4 bv0 = *(const float4*)(bias + c8);
        float4 bv1 = *(const float4*)(bias + c8 + 4);
        float bb[8] = {bv0.x, bv0.y, bv0.z, bv0.w, bv1.x, bv1.y, bv1.z, bv1.w};
        unsigned short ov[8];
#pragma unroll
        for (int j = 0; j < 8; ++j)
            ov[j] = f2bf(fmaxf(fmaf(acc0[j], di, bb[j]), 0.f));
        *(ushort4*)(out + (size_t)wid * 64 + c8) = make_ushort4(ov[0], ov[1], ov[2], ov[3]);
        *(ushort4*)(out + (size_t)wid * 64 + c8 + 4) = make_ushort4(ov[4], ov[5], ov[6], ov[7]);
    }
}

// ---------------- launch ----------------

extern "C" void kernel_launch(void* const* d_in, const int* in_sizes, int n_in,
                              void* d_out, int out_size, void* d_ws, size_t ws_size,
                              hipStream_t stream) {
    const float* x  = (const float*)d_in[0];
    const int*   ei = (const int*)d_in[1];   // int32 (JAX x64 disabled demotes int64)
    const float* W1 = (const float*)d_in[2];
    const float* b1 = (const float*)d_in[3];
    const float* W2 = (const float*)d_in[4];
    const float* b2 = (const float*)d_in[5];
    const float* W3 = (const float*)d_in[6];
    const float* b3 = (const float*)d_in[7];
    const float* W4 = (const float*)d_in[8];
    const float* b4 = (const float*)d_in[9];
    float* outp = (float*)d_out;

    const int N = NNODES;
    const int E = NEDGES;
    const int* srcp = ei;
    const int* dstp = ei + E;

    char* w = (char*)d_ws;
    size_t o = 0;
    auto alloc = [&](size_t bytes) { size_t r = o; o = (o + bytes + 255) & ~(size_t)255; return r; };
    size_t cnt_off   = alloc((size_t)N * 4);
    size_t off_off   = alloc((size_t)N * 4);
    size_t dinv_off  = alloc((size_t)N * 4);
    size_t histg_off = alloc((size_t)SCAN_N * 4);
    size_t gscan_off = alloc((size_t)SCAN_N * 4);
    size_t gbT_off   = alloc((size_t)SCAN_N * 4);
    size_t bs_off    = alloc(256 * 4);
    size_t bse_off   = alloc(256 * 4);
    size_t part_off  = alloc((size_t)E * 4);
    size_t csr_off   = alloc((size_t)E * 4);
    size_t hp_off    = alloc((size_t)(N + 1) * 64 * 2);  // +1 zeroed pad row
    size_t abf_off   = alloc((size_t)N * 64 * 2);
    size_t wp1_off   = alloc(128 * 64 * 2);
    size_t wp2_off   = alloc(64 * 64 * 2);
    size_t wp34_off  = alloc(64 * 64 * 2);
    size_t b34_off   = alloc(64 * 4);

    int*            cnt   = (int*)(w + cnt_off);
    int*            off   = (int*)(w + off_off);
    float*          dinv  = (float*)(w + dinv_off);
    int*            histg = (int*)(w + histg_off);
    int*            gscan = (int*)(w + gscan_off);
    int*            gbT   = (int*)(w + gbT_off);
    int*            bs    = (int*)(w + bs_off);
    int*            bse   = (int*)(w + bse_off);
    unsigned int*   part  = (unsigned int*)(w + part_off);
    int*            csr   = (int*)(w + csr_off);
    unsigned short* hp    = (unsigned short*)(w + hp_off);
    unsigned short* abf   = (unsigned short*)(w + abf_off);
    unsigned short* Wp1   = (unsigned short*)(w + wp1_off);
    unsigned short* Wp2   = (unsigned short*)(w + wp2_off);
    unsigned short* Wp34  = (unsigned short*)(w + wp34_off);
    float*          b34   = (float*)(w + b34_off);

    const int sb = (SCAN_N + 1023) / 1024;   // 196
    const int s3b = (SCAN_N + 255) / 256;    // 783

    hist_kernel<<<PB, 256, 0, stream>>>(dstp, histg);
    scan1_kernel<<<sb, 256, 0, stream>>>(histg, gscan, bs, SCAN_N);
    scan2_kernel<<<1, 256, 0, stream>>>(bs, bse, sb);
    scan3t_kernel<<<s3b, 256, 0, stream>>>(gscan, bse, gbT, SCAN_N);
    part_kernel<<<PB, 256, 0, stream>>>(srcp, dstp, gbT, part);
    csr_kernel<<<NB, 256, 0, stream>>>(part, gbT, csr, cnt, off, dinv, N);

    prep_kernel<<<66, 256, 0, stream>>>(W1, W2, W3, W4, b3, b4, Wp1, Wp2, Wp34, b34, hp);

    const int gb = (N + 63) / 64;       // 1563
    const int ab = (N + 3) / 4;         // 25000

    gemm_mfma_kernel<128, false, true><<<gb, 256, 0, stream>>>(nullptr, x, Wp1, nullptr, dinv, hp, nullptr, N);
    aggregate_kernel<<<ab, 256, 0, stream>>>(hp, csr, off, cnt, dinv, b1, abf, N);
    gemm_mfma_kernel<64, false, false><<<gb, 256, 0, stream>>>(abf, nullptr, Wp2, nullptr, dinv, hp, nullptr, N);
    aggregate_kernel<<<ab, 256, 0, stream>>>(hp, csr, off, cnt, dinv, b2, abf, N);
    gemm_mfma_kernel<64, true, false><<<gb, 256, 0, stream>>>(abf, nullptr, Wp34, b34, nullptr, nullptr, outp, N);
}

// Round 8
// 270.855 us; speedup vs baseline: 1.0672x; 1.0672x over previous
//
#include <hip/hip_runtime.h>
#include <hip/hip_bf16.h>
#include <math.h>

#define NNODES 100000
#define NEDGES 1600000
#define NB 782           // ceil(NNODES/128) buckets of 128 nodes
#define PB 256           // partition blocks
#define EPB 6250         // NEDGES / PB exactly
#define SCAN_N (NB * PB) // 200192
#define CAP 4608         // LDS stage capacity per bucket (avg 2048, max ~2300)

typedef __bf16 bf16x8 __attribute__((ext_vector_type(8)));
typedef float f32x4 __attribute__((ext_vector_type(4)));

static __device__ inline unsigned short f2bf(float f) {
    __hip_bfloat16 h = __float2bfloat16(f);
    return *reinterpret_cast<unsigned short*>(&h);
}

static __device__ inline float bf2f(unsigned short u) {
    unsigned int x = ((unsigned int)u) << 16;
    return __builtin_bit_cast(float, x);
}

// ---------------- pass A: per-block LDS histogram of dst>>7 ----------------

__global__ __launch_bounds__(256) void hist_kernel(const int* __restrict__ dst,
                                                   int* __restrict__ histg) {
    __shared__ int h[NB];
    int tid = threadIdx.x, blk = blockIdx.x;
    for (int b = tid; b < NB; b += 256) h[b] = 0;
    __syncthreads();
    int base = blk * EPB;
    for (int i = base + tid; i < base + EPB; i += 256)
        atomicAdd(&h[dst[i] >> 7], 1);
    __syncthreads();
    for (int b = tid; b < NB; b += 256) histg[b * PB + blk] = h[b];
}

// ---------------- scan chain over SCAN_N elements ----------------

__global__ __launch_bounds__(256) void scan1_kernel(const int* __restrict__ cnt,
                                                    int* __restrict__ off,
                                                    int* __restrict__ bsum, int n) {
    __shared__ int tmp[256];
    int tid = threadIdx.x;
    int t4 = blockIdx.x * 1024 + tid * 4;
    int v0 = (t4 + 0 < n) ? cnt[t4 + 0] : 0;
    int v1 = (t4 + 1 < n) ? cnt[t4 + 1] : 0;
    int v2 = (t4 + 2 < n) ? cnt[t4 + 2] : 0;
    int v3 = (t4 + 3 < n) ? cnt[t4 + 3] : 0;
    int ssum = v0 + v1 + v2 + v3;
    tmp[tid] = ssum;
    __syncthreads();
    for (int d = 1; d < 256; d <<= 1) {
        int x = (tid >= d) ? tmp[tid - d] : 0;
        __syncthreads();
        tmp[tid] += x;
        __syncthreads();
    }
    int run = tmp[tid] - ssum;
    if (t4 + 0 < n) off[t4 + 0] = run; run += v0;
    if (t4 + 1 < n) off[t4 + 1] = run; run += v1;
    if (t4 + 2 < n) off[t4 + 2] = run; run += v2;
    if (t4 + 3 < n) off[t4 + 3] = run;
    if (tid == 255) bsum[blockIdx.x] = tmp[255];
}

__global__ __launch_bounds__(256) void scan2_kernel(const int* __restrict__ bsum,
                                                    int* __restrict__ bsum_ex, int nb) {
    __shared__ int tmp[256];
    int tid = threadIdx.x;
    int v = (tid < nb) ? bsum[tid] : 0;
    tmp[tid] = v;
    __syncthreads();
    for (int d = 1; d < 256; d <<= 1) {
        int x = (tid >= d) ? tmp[tid - d] : 0;
        __syncthreads();
        tmp[tid] += x;
        __syncthreads();
    }
    bsum_ex[tid] = tmp[tid] - v;
}

// finalize scan + emit transposed scan table AND transposed count table
__global__ __launch_bounds__(256) void scan3t_kernel(const int* __restrict__ part_scan,
                                                     const int* __restrict__ bsum_ex,
                                                     const int* __restrict__ histg,
                                                     int* __restrict__ gbaseT,
                                                     int* __restrict__ cntT, int n) {
    int i = blockIdx.x * 256 + threadIdx.x;
    if (i < n) {
        int v = part_scan[i] + bsum_ex[i >> 10];
        int b = i >> 8, blk = i & 255;   // i = b*PB + blk, PB=256
        gbaseT[blk * NB + b] = v;
        cntT[blk * NB + b] = histg[i];
    }
}

// ---------------- pass B: partition via in-LDS counting sort ----------------
// Counts come from cntT (no recount). Edges are placed bucket-sorted in LDS
// together with their global address, then flushed linearly so global writes
// are runs of consecutive u32 (line-coalesced).

__global__ __launch_bounds__(256) void part_kernel(const int* __restrict__ src,
                                                   const int* __restrict__ dst,
                                                   const int* __restrict__ gbaseT,
                                                   const int* __restrict__ cntT,
                                                   unsigned int* __restrict__ part) {
    __shared__ unsigned int sorted[EPB];
    __shared__ int gaddr[EPB];
    __shared__ int gcol[NB];
    __shared__ int base_l[NB];
    __shared__ int cur[NB];
    __shared__ int tmp[256];
    int tid = threadIdx.x, blk = blockIdx.x;
    for (int b = tid; b < NB; b += 256) {
        gcol[b] = gbaseT[blk * NB + b];
        base_l[b] = cntT[blk * NB + b];  // counts, scanned in place below
        cur[b] = 0;
    }
    __syncthreads();
    // exclusive scan of base_l over NB (4 elements per thread)
    int t4 = tid * 4;
    int v0 = (t4 + 0 < NB) ? base_l[t4 + 0] : 0;
    int v1 = (t4 + 1 < NB) ? base_l[t4 + 1] : 0;
    int v2 = (t4 + 2 < NB) ? base_l[t4 + 2] : 0;
    int v3 = (t4 + 3 < NB) ? base_l[t4 + 3] : 0;
    int ssum = v0 + v1 + v2 + v3;
    tmp[tid] = ssum;
    __syncthreads();
    for (int d = 1; d < 256; d <<= 1) {
        int x = (tid >= d) ? tmp[tid - d] : 0;
        __syncthreads();
        tmp[tid] += x;
        __syncthreads();
    }
    int run = tmp[tid] - ssum;
    if (t4 + 0 < NB) base_l[t4 + 0] = run; run += v0;
    if (t4 + 1 < NB) base_l[t4 + 1] = run; run += v1;
    if (t4 + 2 < NB) base_l[t4 + 2] = run; run += v2;
    if (t4 + 3 < NB) base_l[t4 + 3] = run;
    __syncthreads();
    // place edges bucket-sorted into LDS
    int base = blk * EPB;
    for (int i = base + tid; i < base + EPB; i += 256) {
        int s = src[i], d = dst[i];
        int bkt = d >> 7;
        int r = atomicAdd(&cur[bkt], 1);
        int pos = base_l[bkt] + r;
        sorted[pos] = ((unsigned int)(d & 127) << 17) | (unsigned int)s;
        gaddr[pos] = gcol[bkt] + r;
    }
    __syncthreads();
    // linear flush: consecutive lanes -> mostly-consecutive global addresses
    for (int i = tid; i < EPB; i += 256)
        part[gaddr[i]] = sorted[i];
}

// ---------------- pass C: per-bucket CSR build + cnt/off/dinv ----------------

__global__ __launch_bounds__(256) void csr_kernel(const unsigned int* __restrict__ part,
                                                  const int* __restrict__ gbaseT,
                                                  int* __restrict__ csr,
                                                  int* __restrict__ cnt_g,
                                                  int* __restrict__ off_g,
                                                  float* __restrict__ dinv_g, int n) {
    __shared__ unsigned int stage[CAP];
    __shared__ int hist2[128];
    __shared__ int sc[128];
    __shared__ int excl[128];
    __shared__ int cur2[128];
    int tid = threadIdx.x, b = blockIdx.x;
    int S = gbaseT[b];
    int T = (b == NB - 1) ? NEDGES : gbaseT[b + 1];
    int len = T - S;
    bool fit = (len <= CAP);
    if (tid < 128) { hist2[tid] = 0; cur2[tid] = 0; }
    __syncthreads();
    for (int i = tid; i < len; i += 256) {
        unsigned int p = part[S + i];
        if (fit) stage[i] = p;
        atomicAdd(&hist2[p >> 17], 1);
    }
    __syncthreads();
    if (tid < 128) sc[tid] = hist2[tid];
    __syncthreads();
    for (int d = 1; d < 128; d <<= 1) {
        int x = 0;
        if (tid < 128 && tid >= d) x = sc[tid - d];
        __syncthreads();
        if (tid < 128) sc[tid] += x;
        __syncthreads();
    }
    if (tid < 128) {
        int c = hist2[tid];
        int ex = sc[tid] - c;
        excl[tid] = ex;
        int node = b * 128 + tid;
        if (node < n) {
            cnt_g[node] = c;
            off_g[node] = S + ex;
            dinv_g[node] = rsqrtf((float)c + 1.0f);
        }
    }
    __syncthreads();
    for (int i = tid; i < len; i += 256) {
        unsigned int p = fit ? stage[i] : part[S + i];
        int dl = p >> 17;
        int s = (int)(p & 0x1FFFFu);
        int r = atomicAdd(&cur2[dl], 1);
        csr[S + excl[dl] + r] = s;
    }
}

// ---------------- fused prep: packW1, packW2, W34=W3@W4 (packed), b34, pad-row zero ----

static __device__ inline int packidx64(int k, int ch) {
    int s = k >> 5, r5 = k & 31, q = r5 >> 3, ii = r5 & 7;
    int t = ch >> 4, lo = ch & 15;
    int lane = q * 16 + lo;
    return ((t * 2 + s) * 64 + lane) * 8 + ii;
}

__global__ __launch_bounds__(256) void prep_kernel(const float* __restrict__ W1,
                                                   const float* __restrict__ W2,
                                                   const float* __restrict__ W3,
                                                   const float* __restrict__ W4,
                                                   const float* __restrict__ b3,
                                                   const float* __restrict__ b4,
                                                   unsigned short* __restrict__ Wp1,
                                                   unsigned short* __restrict__ Wp2,
                                                   unsigned short* __restrict__ Wp34,
                                                   float* __restrict__ b34,
                                                   unsigned short* __restrict__ hp) {
    int blk = blockIdx.x, tid = threadIdx.x;
    if (blk < 32) {            // packW1, K=128, S=4
        int idx = blk * 256 + tid;
        int i = idx & 7, rest = idx >> 3;
        int lane = rest & 63; rest >>= 6;
        int s = rest % 4, t = rest / 4;
        int k = s * 32 + (lane >> 4) * 8 + i;
        int ch = t * 16 + (lane & 15);
        Wp1[idx] = f2bf(W1[k * 64 + ch]);
    } else if (blk < 48) {     // packW2, K=64, S=2
        int idx = (blk - 32) * 256 + tid;
        int i = idx & 7, rest = idx >> 3;
        int lane = rest & 63; rest >>= 6;
        int s = rest % 2, t = rest / 2;
        int k = s * 32 + (lane >> 4) * 8 + i;
        int ch = t * 16 + (lane & 15);
        Wp2[idx] = f2bf(W2[k * 64 + ch]);
    } else if (blk == 48) {    // zero pad row
        if (tid < 64) hp[(size_t)NNODES * 64 + tid] = 0;
    } else if (blk < 65) {     // W34 compute + pack
        int i = (blk - 49) * 4 + (tid >> 6);
        int j = tid & 63;
        float a = 0.f;
        for (int k = 0; k < 256; ++k) a = fmaf(W3[i * 256 + k], W4[k * 64 + j], a);
        Wp34[packidx64(i, j)] = f2bf(a);
    } else {                   // b34
        if (tid < 64) {
            int j = tid;
            float a = b4[j];
            for (int k = 0; k < 256; ++k) a = fmaf(b3[k], W4[k * 64 + j], a);
            b34[j] = a;
        }
    }
}

// ---------------- MFMA GEMM: out[N,64] = X[N,K] @ W[K,64] ----------------

template <int K, bool LSM, bool F32IN>
__global__ __launch_bounds__(256) void gemm_mfma_kernel(const unsigned short* __restrict__ Xb,
                                                        const float* __restrict__ Xf,
                                                        const unsigned short* __restrict__ Wp,
                                                        const float* __restrict__ bias,
                                                        const float* __restrict__ dinv,
                                                        unsigned short* __restrict__ outb,
                                                        float* __restrict__ outf, int n) {
    constexpr int S = K / 32;
    int w = threadIdx.x >> 6, lane = threadIdx.x & 63;
    int q = lane >> 4, lo = lane & 15;
    int base = blockIdx.x * 64 + w * 16;
    int nodeA = base + lo;
    int na = nodeA < n ? nodeA : 0;

    f32x4 acc[4] = {};
#pragma unroll
    for (int s = 0; s < S; ++s) {
        bf16x8 a;
        if (F32IN) {
            const float* xr = Xf + (size_t)na * K + q * 8 + s * 32;
            float4 u = *(const float4*)(xr);
            float4 v = *(const float4*)(xr + 4);
            a[0] = (__bf16)u.x; a[1] = (__bf16)u.y; a[2] = (__bf16)u.z; a[3] = (__bf16)u.w;
            a[4] = (__bf16)v.x; a[5] = (__bf16)v.y; a[6] = (__bf16)v.z; a[7] = (__bf16)v.w;
        } else {
            a = *(const bf16x8*)(Xb + (size_t)na * K + q * 8 + s * 32);
        }
#pragma unroll
        for (int t = 0; t < 4; ++t) {
            bf16x8 b = *(const bf16x8*)(Wp + ((size_t)(t * S + s) * 64 + lane) * 8);
            acc[t] = __builtin_amdgcn_mfma_f32_16x16x32_bf16(a, b, acc[t], 0, 0, 0);
        }
    }

    if (!LSM) {
#pragma unroll
        for (int r = 0; r < 4; ++r) {
            int node = base + q * 4 + r;
            if (node < n) {
                float di = dinv[node];
#pragma unroll
                for (int t = 0; t < 4; ++t)
                    outb[(size_t)node * 64 + t * 16 + lo] = f2bf(acc[t][r] * di);
            }
        }
    } else {
#pragma unroll
        for (int r = 0; r < 4; ++r) {
            int node = base + q * 4 + r;
            float v0 = acc[0][r] + bias[0 * 16 + lo];
            float v1 = acc[1][r] + bias[1 * 16 + lo];
            float v2 = acc[2][r] + bias[2 * 16 + lo];
            float v3 = acc[3][r] + bias[3 * 16 + lo];
            float mx = fmaxf(fmaxf(v0, v1), fmaxf(v2, v3));
            for (int d = 1; d < 16; d <<= 1) mx = fmaxf(mx, __shfl_xor(mx, d));
            float sm = __expf(v0 - mx) + __expf(v1 - mx) + __expf(v2 - mx) + __expf(v3 - mx);
            for (int d = 1; d < 16; d <<= 1) sm += __shfl_xor(sm, d);
            float lse = mx + __logf(sm);
            if (node < n) {
                outf[(size_t)node * 64 + 0 * 16 + lo] = v0 - lse;
                outf[(size_t)node * 64 + 1 * 16 + lo] = v1 - lse;
                outf[(size_t)node * 64 + 2 * 16 + lo] = v2 - lse;
                outf[(size_t)node * 64 + 3 * 16 + lo] = v3 - lse;
            }
        }
    }
}

// ---------------- aggregation: one wave per dst node (R6-measured form) ----------------

__global__ __launch_bounds__(256) void aggregate_kernel(const unsigned short* __restrict__ hp,
                                                        const int* __restrict__ csr,
                                                        const int* __restrict__ off,
                                                        const int* __restrict__ cnt,
                                                        const float* __restrict__ dinv,
                                                        const float* __restrict__ bias,
                                                        unsigned short* __restrict__ out, int n) {
    int wid = (blockIdx.x * 256 + threadIdx.x) >> 6;
    int lane = threadIdx.x & 63;
    if (wid >= n) return;
    int g = lane >> 3;        // edge slot 0..7
    int c8 = (lane & 7) * 8;  // channel base

    int s = off[wid];
    int c = cnt[wid];

    // preload indices: slots [0,c) = neighbors, slot c = self (if it fits), rest = pad
    int idx = n;
    if (lane < c) idx = csr[s + lane];
    else if (lane == c) idx = wid;   // only reachable when c <= 63

    int m = (c <= 63) ? c + 1 : 64;
    int steps = (m + 7) >> 3;

    float acc0[8] = {}, acc1[8] = {};
    int it = 0;
    for (; it + 2 <= steps; it += 2) {
        int sa = __shfl(idx, it * 8 + g);
        int sb = __shfl(idx, it * 8 + 8 + g);
        bf16x8 va = *(const bf16x8*)(hp + (size_t)sa * 64 + c8);
        bf16x8 vb = *(const bf16x8*)(hp + (size_t)sb * 64 + c8);
#pragma unroll
        for (int j = 0; j < 8; ++j) { acc0[j] += (float)va[j]; acc1[j] += (float)vb[j]; }
    }
    if (it < steps) {
        int sa = __shfl(idx, it * 8 + g);
        bf16x8 va = *(const bf16x8*)(hp + (size_t)sa * 64 + c8);
#pragma unroll
        for (int j = 0; j < 8; ++j) acc0[j] += (float)va[j];
    }

    if (c > 63) {  // rare tail: remaining edges + self-loop
        if (g == 0) {
            bf16x8 v = *(const bf16x8*)(hp + (size_t)wid * 64 + c8);
#pragma unroll
            for (int j = 0; j < 8; ++j) acc1[j] += (float)v[j];
        }
        for (int jj = 64 + g; jj < c; jj += 8) {
            int srcn = csr[s + jj];
            bf16x8 v = *(const bf16x8*)(hp + (size_t)srcn * 64 + c8);
#pragma unroll
            for (int j = 0; j < 8; ++j) acc0[j] += (float)v[j];
        }
    }

#pragma unroll
    for (int j = 0; j < 8; ++j) acc0[j] += acc1[j];

#pragma unroll
    for (int d = 8; d < 64; d <<= 1)
#pragma unroll
        for (int j = 0; j < 8; ++j) acc0[j] += __shfl_xor(acc0[j], d);

    if (lane < 8) {
        float di = dinv[wid];
        float4 bv0 = *(const float4*)(bias + c8);
        float4 bv1 = *(const float4*)(bias + c8 + 4);
        float bb[8] = {bv0.x, bv0.y, bv0.z, bv0.w, bv1.x, bv1.y, bv1.z, bv1.w};
        unsigned short ov[8];
#pragma unroll
        for (int j = 0; j < 8; ++j)
            ov[j] = f2bf(fmaxf(fmaf(acc0[j], di, bb[j]), 0.f));
        *(ushort4*)(out + (size_t)wid * 64 + c8) = make_ushort4(ov[0], ov[1], ov[2], ov[3]);
        *(ushort4*)(out + (size_t)wid * 64 + c8 + 4) = make_ushort4(ov[4], ov[5], ov[6], ov[7]);
    }
}

// ---------------- launch ----------------

extern "C" void kernel_launch(void* const* d_in, const int* in_sizes, int n_in,
                              void* d_out, int out_size, void* d_ws, size_t ws_size,
                              hipStream_t stream) {
    const float* x  = (const float*)d_in[0];
    const int*   ei = (const int*)d_in[1];   // int32 (JAX x64 disabled demotes int64)
    const float* W1 = (const float*)d_in[2];
    const float* b1 = (const float*)d_in[3];
    const float* W2 = (const float*)d_in[4];
    const float* b2 = (const float*)d_in[5];
    const float* W3 = (const float*)d_in[6];
    const float* b3 = (const float*)d_in[7];
    const float* W4 = (const float*)d_in[8];
    const float* b4 = (const float*)d_in[9];
    float* outp = (float*)d_out;

    const int N = NNODES;
    const int E = NEDGES;
    const int* srcp = ei;
    const int* dstp = ei + E;

    char* w = (char*)d_ws;
    size_t o = 0;
    auto alloc = [&](size_t bytes) { size_t r = o; o = (o + bytes + 255) & ~(size_t)255; return r; };
    size_t cnt_off   = alloc((size_t)N * 4);
    size_t off_off   = alloc((size_t)N * 4);
    size_t dinv_off  = alloc((size_t)N * 4);
    size_t histg_off = alloc((size_t)SCAN_N * 4);
    size_t gscan_off = alloc((size_t)SCAN_N * 4);
    size_t gbT_off   = alloc((size_t)SCAN_N * 4);
    size_t cntT_off  = alloc((size_t)SCAN_N * 4);
    size_t bs_off    = alloc(256 * 4);
    size_t bse_off   = alloc(256 * 4);
    size_t part_off  = alloc((size_t)E * 4);
    size_t csr_off   = alloc((size_t)E * 4);
    size_t hp_off    = alloc((size_t)(N + 1) * 64 * 2);  // +1 zeroed pad row
    size_t abf_off   = alloc((size_t)N * 64 * 2);
    size_t wp1_off   = alloc(128 * 64 * 2);
    size_t wp2_off   = alloc(64 * 64 * 2);
    size_t wp34_off  = alloc(64 * 64 * 2);
    size_t b34_off   = alloc(64 * 4);

    int*            cnt   = (int*)(w + cnt_off);
    int*            off   = (int*)(w + off_off);
    float*          dinv  = (float*)(w + dinv_off);
    int*            histg = (int*)(w + histg_off);
    int*            gscan = (int*)(w + gscan_off);
    int*            gbT   = (int*)(w + gbT_off);
    int*            cntT  = (int*)(w + cntT_off);
    int*            bs    = (int*)(w + bs_off);
    int*            bse   = (int*)(w + bse_off);
    unsigned int*   part  = (unsigned int*)(w + part_off);
    int*            csr   = (int*)(w + csr_off);
    unsigned short* hp    = (unsigned short*)(w + hp_off);
    unsigned short* abf   = (unsigned short*)(w + abf_off);
    unsigned short* Wp1   = (unsigned short*)(w + wp1_off);
    unsigned short* Wp2   = (unsigned short*)(w + wp2_off);
    unsigned short* Wp34  = (unsigned short*)(w + wp34_off);
    float*          b34   = (float*)(w + b34_off);

    const int sb = (SCAN_N + 1023) / 1024;   // 196
    const int s3b = (SCAN_N + 255) / 256;    // 783

    hist_kernel<<<PB, 256, 0, stream>>>(dstp, histg);
    scan1_kernel<<<sb, 256, 0, stream>>>(histg, gscan, bs, SCAN_N);
    scan2_kernel<<<1, 256, 0, stream>>>(bs, bse, sb);
    scan3t_kernel<<<s3b, 256, 0, stream>>>(gscan, bse, histg, gbT, cntT, SCAN_N);
    part_kernel<<<PB, 256, 0, stream>>>(srcp, dstp, gbT, cntT, part);
    csr_kernel<<<NB, 256, 0, stream>>>(part, gbT, csr, cnt, off, dinv, N);

    prep_kernel<<<66, 256, 0, stream>>>(W1, W2, W3, W4, b3, b4, Wp1, Wp2, Wp34, b34, hp);

    const int gb = (N + 63) / 64;       // 1563
    const int ab = (N + 3) / 4;         // 25000

    gemm_mfma_kernel<128, false, true><<<gb, 256, 0, stream>>>(nullptr, x, Wp1, nullptr, dinv, hp, nullptr, N);
    aggregate_kernel<<<ab, 256, 0, stream>>>(hp, csr, off, cnt, dinv, b1, abf, N);
    gemm_mfma_kernel<64, false, false><<<gb, 256, 0, stream>>>(abf, nullptr, Wp2, nullptr, dinv, hp, nullptr, N);
    aggregate_kernel<<<ab, 256, 0, stream>>>(hp, csr, off, cnt, dinv, b2, abf, N);
    gemm_mfma_kernel<64, true, false><<<gb, 256, 0, stream>>>(abf, nullptr, Wp34, b34, nullptr, nullptr, outp, N);
}